// Round 14
// baseline (1282.112 us; speedup 1.0000x reference)
//
#include <hip/hip_runtime.h>
#include <hip/hip_bf16.h>

#define NR 4096
#define DIMD 2048
#define NL 32768
#define KTOP 32
#define CAP 224
#define THRQ 2.80f

typedef float f32x4 __attribute__((ext_vector_type(4)));
typedef __bf16 bf16x8 __attribute__((ext_vector_type(8)));

__device__ inline unsigned short f2bf(float f) {
  union { float fl; unsigned u; } v; v.fl = f;
  unsigned u = v.u;
  u = (u + 0x7fffu + ((u >> 16) & 1u)) >> 16;   // RNE; inputs finite
  return (unsigned short)u;
}

__device__ __forceinline__ void gload_lds16(const void* g, void* l) {
  __builtin_amdgcn_global_load_lds(
      (const __attribute__((address_space(1))) unsigned int*)g,
      (__attribute__((address_space(3))) unsigned int*)l, 16, 0, 0);
}

// Per-row: ||x||^2, ||x-b_dec||^2 (threshold), x-b_dec -> bf16.
__global__ __launch_bounds__(256) void k_rowstats(const float* __restrict__ x,
    const float* __restrict__ bdec, unsigned short* __restrict__ xb,
    float* __restrict__ thr, double* __restrict__ sumx2) {
  int row = blockIdx.x, tid = threadIdx.x;
  const float4* xr = (const float4*)(x + (size_t)row * DIMD);
  const float4* bd = (const float4*)bdec;
  ushort4* xbr = (ushort4*)(xb + (size_t)row * DIMD);
  float sx = 0.f, si = 0.f;
  for (int i = tid; i < DIMD / 4; i += 256) {
    float4 v = xr[i]; float4 b = bd[i];
    sx += v.x * v.x + v.y * v.y + v.z * v.z + v.w * v.w;
    float a0 = v.x - b.x, a1 = v.y - b.y, a2 = v.z - b.z, a3 = v.w - b.w;
    si += a0 * a0 + a1 * a1 + a2 * a2 + a3 * a3;
    ushort4 o; o.x = f2bf(a0); o.y = f2bf(a1); o.z = f2bf(a2); o.w = f2bf(a3);
    xbr[i] = o;
  }
  __shared__ double r1[256], r2[256];
  r1[tid] = (double)sx; r2[tid] = (double)si; __syncthreads();
  for (int o = 128; o > 0; o >>= 1) {
    if (tid < o) { r1[tid] += r1[tid + o]; r2[tid] += r2[tid + o]; }
    __syncthreads();
  }
  if (tid == 0) {
    thr[row] = THRQ * sqrtf((float)(r2[0] / (double)DIMD));
    atomicAdd(sumx2, r1[0]);
  }
}

// Column sums of x (mean over axis 0), f64.
__global__ __launch_bounds__(256) void k_colsum(const float* __restrict__ x,
                                                double* __restrict__ colsum) {
  int col = blockIdx.x * 256 + threadIdx.x;
  int r0 = blockIdx.y * 64;
  double s = 0.0;
  for (int r = 0; r < 64; r++) s += (double)x[(size_t)(r0 + r) * DIMD + col];
  atomicAdd(&colsum[col], s);
}

// W_enc f32 -> bf16 (one pass).
__global__ __launch_bounds__(256) void k_convw(const float* __restrict__ w,
                                               unsigned short* __restrict__ wb) {
  size_t total = (size_t)NL * DIMD / 8;
  for (size_t i = (size_t)blockIdx.x * 256 + threadIdx.x; i < total;
       i += (size_t)gridDim.x * 256) {
    float4 a = ((const float4*)w)[2 * i], b = ((const float4*)w)[2 * i + 1];
    ushort4 o1, o2;
    o1.x = f2bf(a.x); o1.y = f2bf(a.y); o1.z = f2bf(a.z); o1.w = f2bf(a.w);
    o2.x = f2bf(b.x); o2.y = f2bf(b.y); o2.z = f2bf(b.z); o2.w = f2bf(b.w);
    ((ushort4*)wb)[2 * i] = o1; ((ushort4*)wb)[2 * i + 1] = o2;
  }
}

// 256x256 tile, 8-wave, 2-LONG-phase pipeline. LDS [buf][ks][row 0..255][64B];
// publish unit = ks-half (A+B), issued a full kt (2 phases ~3000cy) before its
// wait -> vmcnt tails ~0. Slot-XOR (row>>1)&3 over 4 slots: each 8-lane group
// covers all 8 granules of the 128B wrap -> conflict-free (r12-verified model).
// Per-acc MFMA order identical to r13 (ks0 then ks1 per kt) -> bit-identical.
__global__ __launch_bounds__(512, 2) void k_gemm4(const unsigned short* __restrict__ xb,
    const unsigned short* __restrict__ wb, const float* __restrict__ benc,
    const float* __restrict__ thr, int* __restrict__ cnt, int* __restrict__ cand,
    float* __restrict__ candv) {
  __shared__ __align__(16) char lds[131072];   // A at 0, B at 65536; buf stride 32768, ks stride 16384
  int tid = threadIdx.x;
  int wv = tid >> 6, lane = tid & 63;
  int wm = wv >> 2, wn = wv & 3;               // 2M x 4N waves
  int lq = lane >> 4, lr = lane & 15;
  int bid = blockIdx.x;
  int xcd = bid & 7, chunk = bid >> 3;         // 2048 blocks, %8==0 bijective
  int ntile = xcd * 16 + (chunk >> 4);
  int mtile = chunk & 15;
  const unsigned short* Ag = xb + (size_t)(mtile * 256) * DIMD;
  const unsigned short* Bg = wb + (size_t)(ntile * 256) * DIMD;

  f32x4 acc[8][4];
#pragma unroll
  for (int m = 0; m < 8; m++)
#pragma unroll
    for (int n = 0; n < 4; n++) { acc[m][n][0] = 0.f; acc[m][n][1] = 0.f; acc[m][n][2] = 0.f; acc[m][n][3] = 0.f; }

  // Staging: unit = 256 rows x 64B = 1024 chunks; thread t -> chunks t, t+512.
  // chunk c: row=c>>2, slot=c&3; source k-slot = slot ^ ((row>>1)&3) (inverse
  // of read XOR); dest linear c*16.
  int c0 = tid, c1 = tid + 512;
  int r0c = c0 >> 2, r1c = c1 >> 2;
  size_t gsrc0 = (size_t)r0c * DIMD + (size_t)(((c0 & 3) ^ ((r0c >> 1) & 3)) * 8);
  size_t gsrc1 = (size_t)r1c * DIMD + (size_t)(((c1 & 3) ^ ((r1c >> 1) & 3)) * 8);
  int d0 = c0 * 16, d1 = c1 * 16;
#define STAGEU(gb, koff, loff) { \
    gload_lds16((gb) + gsrc0 + (koff), lds + (loff) + d0); \
    gload_lds16((gb) + gsrc1 + (koff), lds + (loff) + d1); }

  // read byte-cols (f independent of m/n since m*32,n*64 are 0 mod 4 after >>1)
  int fA = ((wm * 8) + (lr >> 1)) & 3;
  int fB = ((wn * 8) + (lr >> 1)) & 3;
  int colA = (lq ^ fA) << 4;
  int colB = (lq ^ fB) << 4;

#define WAITV(N) { asm volatile("s_waitcnt vmcnt(" #N ")" ::: "memory"); \
                   __builtin_amdgcn_sched_barrier(0); }

  // prologue: tile 0 (ks0 pair then ks1 pair) into buf0
  STAGEU(Ag, 0, 0);
  STAGEU(Bg, 0, 65536);
  STAGEU(Ag, 32, 16384);
  STAGEU(Bg, 32, 65536 + 16384);

  for (int kt = 0; kt < 32; kt++) {
    int cur = kt & 1, nxt = cur ^ 1;
    bool pre = (kt < 31);
    const unsigned short* Agn = Ag + (kt + 1) * 64;
    const unsigned short* Bgn = Bg + (kt + 1) * 64;
#pragma unroll
    for (int ks = 0; ks < 2; ks++) {
      // wait for ks(kt) unit: queue = ks(kt) A+B (4) [+ newer 4 if any]
      if (kt == 31 && ks == 1) { WAITV(0); } else { WAITV(4); }
      __builtin_amdgcn_s_barrier();
      if (pre) {
        STAGEU(Agn, ks * 32, nxt * 32768 + ks * 16384);
        STAGEU(Bgn, ks * 32, 65536 + nxt * 32768 + ks * 16384);
      }
      const char* Ac = lds + cur * 32768 + ks * 16384;
      const char* Bc = lds + 65536 + cur * 32768 + ks * 16384;
      bf16x8 b0 = *(const bf16x8*)(Bc + (0 * 64 + wn * 16 + lr) * 64 + colB);
      bf16x8 b1 = *(const bf16x8*)(Bc + (1 * 64 + wn * 16 + lr) * 64 + colB);
      bf16x8 b2 = *(const bf16x8*)(Bc + (2 * 64 + wn * 16 + lr) * 64 + colB);
      bf16x8 b3 = *(const bf16x8*)(Bc + (3 * 64 + wn * 16 + lr) * 64 + colB);
      bf16x8 a0 = *(const bf16x8*)(Ac + (0 * 32 + wm * 16 + lr) * 64 + colA);
      bf16x8 a1 = *(const bf16x8*)(Ac + (1 * 32 + wm * 16 + lr) * 64 + colA);
      bf16x8 a2 = *(const bf16x8*)(Ac + (2 * 32 + wm * 16 + lr) * 64 + colA);
      bf16x8 a3 = *(const bf16x8*)(Ac + (3 * 32 + wm * 16 + lr) * 64 + colA);
      bf16x8 a4 = *(const bf16x8*)(Ac + (4 * 32 + wm * 16 + lr) * 64 + colA);
      bf16x8 a5 = *(const bf16x8*)(Ac + (5 * 32 + wm * 16 + lr) * 64 + colA);
      bf16x8 a6 = *(const bf16x8*)(Ac + (6 * 32 + wm * 16 + lr) * 64 + colA);
      bf16x8 a7 = *(const bf16x8*)(Ac + (7 * 32 + wm * 16 + lr) * 64 + colA);
      __builtin_amdgcn_s_setprio(1);
#pragma unroll
      for (int n = 0; n < 4; n++) {
        bf16x8 bn = (n == 0) ? b0 : (n == 1) ? b1 : (n == 2) ? b2 : b3;
        acc[0][n] = __builtin_amdgcn_mfma_f32_16x16x32_bf16(a0, bn, acc[0][n], 0, 0, 0);
        acc[1][n] = __builtin_amdgcn_mfma_f32_16x16x32_bf16(a1, bn, acc[1][n], 0, 0, 0);
        acc[2][n] = __builtin_amdgcn_mfma_f32_16x16x32_bf16(a2, bn, acc[2][n], 0, 0, 0);
        acc[3][n] = __builtin_amdgcn_mfma_f32_16x16x32_bf16(a3, bn, acc[3][n], 0, 0, 0);
        acc[4][n] = __builtin_amdgcn_mfma_f32_16x16x32_bf16(a4, bn, acc[4][n], 0, 0, 0);
        acc[5][n] = __builtin_amdgcn_mfma_f32_16x16x32_bf16(a5, bn, acc[5][n], 0, 0, 0);
        acc[6][n] = __builtin_amdgcn_mfma_f32_16x16x32_bf16(a6, bn, acc[6][n], 0, 0, 0);
        acc[7][n] = __builtin_amdgcn_mfma_f32_16x16x32_bf16(a7, bn, acc[7][n], 0, 0, 0);
      }
      __builtin_amdgcn_s_setprio(0);
    }
  }
#undef STAGEU
#undef WAITV
  // Epilogue: + b_enc, threshold filter, append candidates (+ approx value).
#pragma unroll
  for (int m = 0; m < 8; m++) {
    int rbase = mtile * 256 + m * 32 + wm * 16 + lq * 4;
#pragma unroll
    for (int j = 0; j < 4; j++) {
      int grow = rbase + j;
      float tv = thr[grow];
#pragma unroll
      for (int n = 0; n < 4; n++) {
        int gcol = ntile * 256 + n * 64 + wn * 16 + lr;
        float v = acc[m][n][j] + benc[gcol];
        if (v > tv) {
          int p = atomicAdd(&cnt[grow], 1);
          if (p < CAP) { cand[grow * CAP + p] = gcol; candv[grow * CAP + p] = v; }
        }
      }
    }
  }
}

// Two-stage refine (r13): approx cutoff, exact BLIS KC=512 chains only above it,
// then top-32 by (f32 exact desc, idx asc).
__global__ __launch_bounds__(256) void k_refine_top32(const float* __restrict__ x,
    const float* __restrict__ bdec, const float* __restrict__ w,
    const float* __restrict__ benc, const int* __restrict__ cnt,
    const int* __restrict__ cand, const float* __restrict__ candv,
    const float* __restrict__ thr, float* __restrict__ out,
    float* __restrict__ acts, int* __restrict__ aidx) {
  int row = blockIdx.x, tid = threadIdx.x;
  __shared__ float xs[DIMD];
  __shared__ float sv[256]; __shared__ int sl[256];
  __shared__ float rv[256]; __shared__ int rl[256]; __shared__ int rs[256];
  __shared__ float a32s;
  const float* xr = x + (size_t)row * DIMD;
  for (int i = tid; i < DIMD; i += 256) xs[i] = xr[i] - bdec[i];
  int c = min(cnt[row], CAP);
  float mya = -3.0e38f; int mylat = 0x7fffffff;
  if (tid < c) { mya = candv[row * CAP + tid]; mylat = cand[row * CAP + tid]; }
  sv[tid] = mya;
  __syncthreads();
  for (int it = 0; it < KTOP; it++) {
    rv[tid] = sv[tid]; rs[tid] = tid;
    __syncthreads();
    for (int o = 128; o > 0; o >>= 1) {
      if (tid < o) {
        if (rv[tid + o] > rv[tid]) { rv[tid] = rv[tid + o]; rs[tid] = rs[tid + o]; }
      }
      __syncthreads();
    }
    if (tid == 0) { sv[rs[0]] = -3.0e38f; if (it == KTOP - 1) a32s = rv[0]; }
    __syncthreads();
  }
  float cutoff = a32s - 0.008f * thr[row];
  float myv = -3.0e38f;
  if (mya >= cutoff) {
    const float* wr = w + (size_t)mylat * DIMD;
    const int pb[5] = {0, 512, 1024, 1536, 2048};
    float accv = 0.f;
#pragma unroll
    for (int p = 0; p < 4; p++) {
      float s = 0.f;
      for (int k = pb[p]; k < pb[p + 1]; k += 4) {
        float4 wv = *(const float4*)(wr + k);
        s = fmaf(xs[k],     wv.x, s);
        s = fmaf(xs[k + 1], wv.y, s);
        s = fmaf(xs[k + 2], wv.z, s);
        s = fmaf(xs[k + 3], wv.w, s);
      }
      accv += s;
    }
    myv = accv + benc[mylat];
  }
  sv[tid] = myv; sl[tid] = (myv > -2.9e38f) ? mylat : 0x7fffffff;
  __syncthreads();
  for (int it = 0; it < KTOP; it++) {
    rv[tid] = sv[tid]; rl[tid] = sl[tid]; rs[tid] = tid;
    __syncthreads();
    for (int o = 128; o > 0; o >>= 1) {
      if (tid < o) {
        bool take = (rv[tid + o] > rv[tid]) ||
                    (rv[tid + o] == rv[tid] && rl[tid + o] < rl[tid]);
        if (take) { rv[tid] = rv[tid + o]; rl[tid] = rl[tid + o]; rs[tid] = rs[tid + o]; }
      }
      __syncthreads();
    }
    if (tid == 0) {
      float av = rv[0]; int al = rl[0];
      if (av < -2.9e38f) { av = 0.f; al = 0; }
      out[(size_t)NR * DIMD + row * KTOP + it] = av;
      out[(size_t)NR * DIMD + (size_t)NR * KTOP + row * KTOP + it] = (float)al;
      acts[row * KTOP + it] = av; aidx[row * KTOP + it] = al;
      sv[rs[0]] = -3.0e38f;
    }
    __syncthreads();
  }
}

// Sparse decode + sum(e^2).
__global__ __launch_bounds__(256) void k_saeout(const float* __restrict__ x,
    const float* __restrict__ wdec, const float* __restrict__ bdec,
    const float* __restrict__ acts, const int* __restrict__ aidx,
    float* __restrict__ out, double* __restrict__ sume2) {
  int row = blockIdx.x, tid = threadIdx.x;
  __shared__ float sa[KTOP]; __shared__ int si[KTOP];
  if (tid < KTOP) { sa[tid] = acts[row * KTOP + tid]; si[tid] = aidx[row * KTOP + tid]; }
  __syncthreads();
  int c0 = tid * 4, c1 = 1024 + tid * 4;
  float a00 = 0, a01 = 0, a02 = 0, a03 = 0, a10 = 0, a11 = 0, a12 = 0, a13 = 0;
  for (int k = 0; k < KTOP; k++) {
    const float* wr = wdec + (size_t)si[k] * DIMD;
    float av = sa[k];
    float4 w0 = *(const float4*)(wr + c0);
    float4 w1 = *(const float4*)(wr + c1);
    a00 += av * w0.x; a01 += av * w0.y; a02 += av * w0.z; a03 += av * w0.w;
    a10 += av * w1.x; a11 += av * w1.y; a12 += av * w1.z; a13 += av * w1.w;
  }
  float4 b0 = *(const float4*)(bdec + c0), b1 = *(const float4*)(bdec + c1);
  a00 += b0.x; a01 += b0.y; a02 += b0.z; a03 += b0.w;
  a10 += b1.x; a11 += b1.y; a12 += b1.z; a13 += b1.w;
  const float* xr = x + (size_t)row * DIMD;
  float4 x0 = *(const float4*)(xr + c0), x1 = *(const float4*)(xr + c1);
  float4 o0, o1;
  o0.x = a00; o0.y = a01; o0.z = a02; o0.w = a03;
  o1.x = a10; o1.y = a11; o1.z = a12; o1.w = a13;
  *(float4*)(out + (size_t)row * DIMD + c0) = o0;
  *(float4*)(out + (size_t)row * DIMD + c1) = o1;
  double es = 0.0; float e;
  e = x0.x - a00; es += (double)e * e; e = x0.y - a01; es += (double)e * e;
  e = x0.z - a02; es += (double)e * e; e = x0.w - a03; es += (double)e * e;
  e = x1.x - a10; es += (double)e * e; e = x1.y - a11; es += (double)e * e;
  e = x1.z - a12; es += (double)e * e; e = x1.w - a13; es += (double)e * e;
  __shared__ double red[256];
  red[tid] = es; __syncthreads();
  for (int o = 128; o > 0; o >>= 1) { if (tid < o) red[tid] += red[tid + o]; __syncthreads(); }
  if (tid == 0) atomicAdd(sume2, red[0]);
}

__global__ __launch_bounds__(256) void k_final(const double* __restrict__ colsum,
    const double* __restrict__ sumx2, const double* __restrict__ sume2,
    float* __restrict__ out) {
  int tid = threadIdx.x;
  double s = 0.0;
  for (int i = tid; i < DIMD; i += 256) { double v = colsum[i]; s += v * v; }
  __shared__ double red[256];
  red[tid] = s; __syncthreads();
  for (int o = 128; o > 0; o >>= 1) { if (tid < o) red[tid] += red[tid + o]; __syncthreads(); }
  if (tid == 0) {
    double tv = *sumx2 - red[0] / (double)NR;
    double fvu = *sume2 / tv;
    size_t base = (size_t)NR * DIMD + 2 * (size_t)NR * KTOP;
    out[base] = (float)fvu;
    out[base + 1] = 0.f;
    out[base + 2] = 0.f;
  }
}

extern "C" void kernel_launch(void* const* d_in, const int* in_sizes, int n_in,
                              void* d_out, int out_size, void* d_ws, size_t ws_size,
                              hipStream_t stream) {
  const float* x    = (const float*)d_in[0];
  const float* wenc = (const float*)d_in[1];
  const float* benc = (const float*)d_in[2];
  const float* wdec = (const float*)d_in[3];
  const float* bdec = (const float*)d_in[4];
  float* out = (float*)d_out;
  char* ws = (char*)d_ws;

  unsigned short* xb  = (unsigned short*)(ws + 0);              // 16,777,216
  float* thr          = (float*)(ws + 16777216);                // 16,384
  int* cnt            = (int*)(ws + 16793600);                  // 16,384
  int* cand           = (int*)(ws + 16809984);                  // 3,670,016
  float* acts         = (float*)(ws + 20480000);                // 524,288
  int* aidx           = (int*)(ws + 21004288);                  // 524,288
  double* colsum      = (double*)(ws + 21528576);               // 16,384
  double* sumx2       = (double*)(ws + 21544960);               // 8
  double* sume2       = sumx2 + 1;                              // 8
  unsigned short* wb  = (unsigned short*)(ws + 22020096);       // 134,217,728
  float* candv        = (float*)(ws + 156237824);               // 3,670,016

  hipMemsetAsync(cnt, 0, 4096 * 4, stream);
  hipMemsetAsync(colsum, 0, 2048 * 8 + 16, stream);

  k_rowstats<<<NR, 256, 0, stream>>>(x, bdec, xb, thr, sumx2);
  k_colsum<<<dim3(8, 64), 256, 0, stream>>>(x, colsum);
  k_convw<<<2048, 256, 0, stream>>>(wenc, wb);
  k_gemm4<<<2048, 512, 0, stream>>>(xb, wb, benc, thr, cnt, cand, candv);
  k_refine_top32<<<NR, 256, 0, stream>>>(x, bdec, wenc, benc, cnt, cand, candv, thr, out, acts, aidx);
  k_saeout<<<NR, 256, 0, stream>>>(x, wdec, bdec, acts, aidx, out, sume2);
  k_final<<<1, 256, 0, stream>>>(colsum, sumx2, sume2, out);
}

// Round 15
// 1047.540 us; speedup vs baseline: 1.2239x; 1.2239x over previous
//
#include <hip/hip_runtime.h>
#include <hip/hip_bf16.h>

#define NR 4096
#define DIMD 2048
#define NL 32768
#define KTOP 32
#define CAP 224
#define THRQ 2.80f

typedef float f32x4 __attribute__((ext_vector_type(4)));
typedef __bf16 bf16x8 __attribute__((ext_vector_type(8)));

__device__ inline unsigned short f2bf(float f) {
  union { float fl; unsigned u; } v; v.fl = f;
  unsigned u = v.u;
  u = (u + 0x7fffu + ((u >> 16) & 1u)) >> 16;   // RNE; inputs finite
  return (unsigned short)u;
}

__device__ __forceinline__ void gload_lds16(const void* g, void* l) {
  __builtin_amdgcn_global_load_lds(
      (const __attribute__((address_space(1))) unsigned int*)g,
      (__attribute__((address_space(3))) unsigned int*)l, 16, 0, 0);
}

// Per-row: ||x||^2, ||x-b_dec||^2 (threshold), x-b_dec -> bf16.
__global__ __launch_bounds__(256) void k_rowstats(const float* __restrict__ x,
    const float* __restrict__ bdec, unsigned short* __restrict__ xb,
    float* __restrict__ thr, double* __restrict__ sumx2) {
  int row = blockIdx.x, tid = threadIdx.x;
  const float4* xr = (const float4*)(x + (size_t)row * DIMD);
  const float4* bd = (const float4*)bdec;
  ushort4* xbr = (ushort4*)(xb + (size_t)row * DIMD);
  float sx = 0.f, si = 0.f;
  for (int i = tid; i < DIMD / 4; i += 256) {
    float4 v = xr[i]; float4 b = bd[i];
    sx += v.x * v.x + v.y * v.y + v.z * v.z + v.w * v.w;
    float a0 = v.x - b.x, a1 = v.y - b.y, a2 = v.z - b.z, a3 = v.w - b.w;
    si += a0 * a0 + a1 * a1 + a2 * a2 + a3 * a3;
    ushort4 o; o.x = f2bf(a0); o.y = f2bf(a1); o.z = f2bf(a2); o.w = f2bf(a3);
    xbr[i] = o;
  }
  __shared__ double r1[256], r2[256];
  r1[tid] = (double)sx; r2[tid] = (double)si; __syncthreads();
  for (int o = 128; o > 0; o >>= 1) {
    if (tid < o) { r1[tid] += r1[tid + o]; r2[tid] += r2[tid + o]; }
    __syncthreads();
  }
  if (tid == 0) {
    thr[row] = THRQ * sqrtf((float)(r2[0] / (double)DIMD));
    atomicAdd(sumx2, r1[0]);
  }
}

// Column sums of x (mean over axis 0), f64.
__global__ __launch_bounds__(256) void k_colsum(const float* __restrict__ x,
                                                double* __restrict__ colsum) {
  int col = blockIdx.x * 256 + threadIdx.x;
  int r0 = blockIdx.y * 64;
  double s = 0.0;
  for (int r = 0; r < 64; r++) s += (double)x[(size_t)(r0 + r) * DIMD + col];
  atomicAdd(&colsum[col], s);
}

// W_enc f32 -> bf16 (one pass).
__global__ __launch_bounds__(256) void k_convw(const float* __restrict__ w,
                                               unsigned short* __restrict__ wb) {
  size_t total = (size_t)NL * DIMD / 8;
  for (size_t i = (size_t)blockIdx.x * 256 + threadIdx.x; i < total;
       i += (size_t)gridDim.x * 256) {
    float4 a = ((const float4*)w)[2 * i], b = ((const float4*)w)[2 * i + 1];
    ushort4 o1, o2;
    o1.x = f2bf(a.x); o1.y = f2bf(a.y); o1.z = f2bf(a.z); o1.w = f2bf(a.w);
    o2.x = f2bf(b.x); o2.y = f2bf(b.y); o2.z = f2bf(b.z); o2.w = f2bf(b.w);
    ((ushort4*)wb)[2 * i] = o1; ((ushort4*)wb)[2 * i + 1] = o2;
  }
}

// r13 gemm (the measured 585us / MfmaUtil 42% local optimum): 256x256 tile,
// 8-wave, 4-phase fragment-reuse pipeline, 128B rows, (row&7) chunk-XOR,
// row-half publish units, counted vmcnt(2), setprio around MFMA clusters.
__global__ __launch_bounds__(512, 2) void k_gemm3(const unsigned short* __restrict__ xb,
    const unsigned short* __restrict__ wb, const float* __restrict__ benc,
    const float* __restrict__ thr, int* __restrict__ cnt, int* __restrict__ cand,
    float* __restrict__ candv) {
  __shared__ __align__(16) char lds[131072];
  int tid = threadIdx.x;
  int wv = tid >> 6, lane = tid & 63;
  int wm = wv >> 2, wn = wv & 3;
  int lq = lane >> 4, lr = lane & 15;
  int bid = blockIdx.x;
  int xcd = bid & 7, chunk = bid >> 3;
  int ntile = xcd * 16 + (chunk >> 4);
  int mtile = chunk & 15;
  const unsigned short* Ag = xb + (size_t)(mtile * 256) * DIMD;
  const unsigned short* Bg = wb + (size_t)(ntile * 256) * DIMD;

  f32x4 acc[8][4];
#pragma unroll
  for (int m = 0; m < 8; m++)
#pragma unroll
    for (int n = 0; n < 4; n++) { acc[m][n][0] = 0.f; acc[m][n][1] = 0.f; acc[m][n][2] = 0.f; acc[m][n][3] = 0.f; }

  int ra0 = tid >> 3;
  int sa0 = ((tid & 7) ^ (ra0 & 7)) * 8;
#define STAGEU(gb, r0, loff) { \
    gload_lds16((gb) + (size_t)((r0) + ra0) * DIMD + sa0, lds + (loff) + tid * 16); \
    gload_lds16((gb) + (size_t)((r0) + ra0 + 64) * DIMD + sa0, lds + (loff) + tid * 16 + 8192); }

  int s0 = (lq ^ (lr & 7)) << 4;

#define WAITV(N) { asm volatile("s_waitcnt vmcnt(" #N ")" ::: "memory"); \
                   __builtin_amdgcn_sched_barrier(0); }

#define MFMA16(mb, A0, A1, A2, A3, B0, B1, B2, B3) { \
    __builtin_amdgcn_s_setprio(1); \
    acc[(mb)+0][0] = __builtin_amdgcn_mfma_f32_16x16x32_bf16(A0, B0, acc[(mb)+0][0], 0, 0, 0); \
    acc[(mb)+1][0] = __builtin_amdgcn_mfma_f32_16x16x32_bf16(A1, B0, acc[(mb)+1][0], 0, 0, 0); \
    acc[(mb)+2][0] = __builtin_amdgcn_mfma_f32_16x16x32_bf16(A2, B0, acc[(mb)+2][0], 0, 0, 0); \
    acc[(mb)+3][0] = __builtin_amdgcn_mfma_f32_16x16x32_bf16(A3, B0, acc[(mb)+3][0], 0, 0, 0); \
    acc[(mb)+0][1] = __builtin_amdgcn_mfma_f32_16x16x32_bf16(A0, B1, acc[(mb)+0][1], 0, 0, 0); \
    acc[(mb)+1][1] = __builtin_amdgcn_mfma_f32_16x16x32_bf16(A1, B1, acc[(mb)+1][1], 0, 0, 0); \
    acc[(mb)+2][1] = __builtin_amdgcn_mfma_f32_16x16x32_bf16(A2, B1, acc[(mb)+2][1], 0, 0, 0); \
    acc[(mb)+3][1] = __builtin_amdgcn_mfma_f32_16x16x32_bf16(A3, B1, acc[(mb)+3][1], 0, 0, 0); \
    acc[(mb)+0][2] = __builtin_amdgcn_mfma_f32_16x16x32_bf16(A0, B2, acc[(mb)+0][2], 0, 0, 0); \
    acc[(mb)+1][2] = __builtin_amdgcn_mfma_f32_16x16x32_bf16(A1, B2, acc[(mb)+1][2], 0, 0, 0); \
    acc[(mb)+2][2] = __builtin_amdgcn_mfma_f32_16x16x32_bf16(A2, B2, acc[(mb)+2][2], 0, 0, 0); \
    acc[(mb)+3][2] = __builtin_amdgcn_mfma_f32_16x16x32_bf16(A3, B2, acc[(mb)+3][2], 0, 0, 0); \
    acc[(mb)+0][3] = __builtin_amdgcn_mfma_f32_16x16x32_bf16(A0, B3, acc[(mb)+0][3], 0, 0, 0); \
    acc[(mb)+1][3] = __builtin_amdgcn_mfma_f32_16x16x32_bf16(A1, B3, acc[(mb)+1][3], 0, 0, 0); \
    acc[(mb)+2][3] = __builtin_amdgcn_mfma_f32_16x16x32_bf16(A2, B3, acc[(mb)+2][3], 0, 0, 0); \
    acc[(mb)+3][3] = __builtin_amdgcn_mfma_f32_16x16x32_bf16(A3, B3, acc[(mb)+3][3], 0, 0, 0); \
    __builtin_amdgcn_s_setprio(0); }

  STAGEU(Ag, 0, 0);
  STAGEU(Bg, 0, 65536);
  STAGEU(Bg, 128, 65536 + 16384);
  STAGEU(Ag, 128, 16384);

  for (int kt = 0; kt < 32; kt++) {
    int cur = kt & 1, nxt = cur ^ 1;
    bool pre = (kt < 31);
    const unsigned short* Agn = Ag + (kt + 1) * 64;
    const unsigned short* Bgn = Bg + (kt + 1) * 64;
    const char* Ac = lds + cur * 32768;
    const char* Bc = lds + 65536 + cur * 32768;
    WAITV(2);
    __builtin_amdgcn_s_barrier();
    if (pre) STAGEU(Agn, 0, nxt * 32768);
    bf16x8 b0 = *(const bf16x8*)(Bc + (0 * 64 + wn * 16 + lr) * 128 + s0);
    bf16x8 b1 = *(const bf16x8*)(Bc + (1 * 64 + wn * 16 + lr) * 128 + s0);
    bf16x8 b2 = *(const bf16x8*)(Bc + (2 * 64 + wn * 16 + lr) * 128 + s0);
    bf16x8 b3 = *(const bf16x8*)(Bc + (3 * 64 + wn * 16 + lr) * 128 + s0);
    {
      bf16x8 a0 = *(const bf16x8*)(Ac + (0 * 32 + wm * 16 + lr) * 128 + s0);
      bf16x8 a1 = *(const bf16x8*)(Ac + (1 * 32 + wm * 16 + lr) * 128 + s0);
      bf16x8 a2 = *(const bf16x8*)(Ac + (2 * 32 + wm * 16 + lr) * 128 + s0);
      bf16x8 a3 = *(const bf16x8*)(Ac + (3 * 32 + wm * 16 + lr) * 128 + s0);
      MFMA16(0, a0, a1, a2, a3, b0, b1, b2, b3);
    }
    if (pre) { WAITV(2); } else { WAITV(0); }
    __builtin_amdgcn_s_barrier();
    if (pre) STAGEU(Bgn, 0, 65536 + nxt * 32768);
    {
      bf16x8 a0 = *(const bf16x8*)(Ac + (4 * 32 + wm * 16 + lr) * 128 + s0);
      bf16x8 a1 = *(const bf16x8*)(Ac + (5 * 32 + wm * 16 + lr) * 128 + s0);
      bf16x8 a2 = *(const bf16x8*)(Ac + (6 * 32 + wm * 16 + lr) * 128 + s0);
      bf16x8 a3 = *(const bf16x8*)(Ac + (7 * 32 + wm * 16 + lr) * 128 + s0);
      MFMA16(4, a0, a1, a2, a3, b0, b1, b2, b3);
    }
    if (pre) STAGEU(Bgn, 128, 65536 + nxt * 32768 + 16384);
    b0 = *(const bf16x8*)(Bc + (0 * 64 + wn * 16 + lr) * 128 + (s0 ^ 64));
    b1 = *(const bf16x8*)(Bc + (1 * 64 + wn * 16 + lr) * 128 + (s0 ^ 64));
    b2 = *(const bf16x8*)(Bc + (2 * 64 + wn * 16 + lr) * 128 + (s0 ^ 64));
    b3 = *(const bf16x8*)(Bc + (3 * 64 + wn * 16 + lr) * 128 + (s0 ^ 64));
    {
      bf16x8 a0 = *(const bf16x8*)(Ac + (0 * 32 + wm * 16 + lr) * 128 + (s0 ^ 64));
      bf16x8 a1 = *(const bf16x8*)(Ac + (1 * 32 + wm * 16 + lr) * 128 + (s0 ^ 64));
      bf16x8 a2 = *(const bf16x8*)(Ac + (2 * 32 + wm * 16 + lr) * 128 + (s0 ^ 64));
      bf16x8 a3 = *(const bf16x8*)(Ac + (3 * 32 + wm * 16 + lr) * 128 + (s0 ^ 64));
      MFMA16(0, a0, a1, a2, a3, b0, b1, b2, b3);
    }
    if (pre) STAGEU(Agn, 128, nxt * 32768 + 16384);
    {
      bf16x8 a0 = *(const bf16x8*)(Ac + (4 * 32 + wm * 16 + lr) * 128 + (s0 ^ 64));
      bf16x8 a1 = *(const bf16x8*)(Ac + (5 * 32 + wm * 16 + lr) * 128 + (s0 ^ 64));
      bf16x8 a2 = *(const bf16x8*)(Ac + (6 * 32 + wm * 16 + lr) * 128 + (s0 ^ 64));
      bf16x8 a3 = *(const bf16x8*)(Ac + (7 * 32 + wm * 16 + lr) * 128 + (s0 ^ 64));
      MFMA16(4, a0, a1, a2, a3, b0, b1, b2, b3);
    }
  }
#undef STAGEU
#undef WAITV
#undef MFMA16
#pragma unroll
  for (int m = 0; m < 8; m++) {
    int rbase = mtile * 256 + m * 32 + wm * 16 + lq * 4;
#pragma unroll
    for (int j = 0; j < 4; j++) {
      int grow = rbase + j;
      float tv = thr[grow];
#pragma unroll
      for (int n = 0; n < 4; n++) {
        int gcol = ntile * 256 + n * 64 + wn * 16 + lr;
        float v = acc[m][n][j] + benc[gcol];
        if (v > tv) {
          int p = atomicAdd(&cnt[grow], 1);
          if (p < CAP) { cand[grow * CAP + p] = gcol; candv[grow * CAP + p] = v; }
        }
      }
    }
  }
}

// Fused refine + top32 + sparse-decode + e^2. Selection via all-pairs ranking
// (2 barriers, no serial extraction): rank_i = #{j: vj>vi || (vj==vi && lj<li)}
// -- identical total order to the old extraction loop.
__global__ __launch_bounds__(256) void k_refine_saeout(const float* __restrict__ x,
    const float* __restrict__ bdec, const float* __restrict__ w,
    const float* __restrict__ benc, const int* __restrict__ cnt,
    const int* __restrict__ cand, const float* __restrict__ candv,
    const float* __restrict__ thr, const float* __restrict__ wdec,
    float* __restrict__ out, double* __restrict__ sume2) {
  int row = blockIdx.x, tid = threadIdx.x;
  __shared__ float xs[DIMD];                  // 8 KB
  __shared__ float sv[256]; __shared__ int sl[256];
  __shared__ float sa[KTOP]; __shared__ int si[KTOP];
  __shared__ float a32s;
  __shared__ double red[256];                 // 2 KB
  const float* xr = x + (size_t)row * DIMD;
  for (int i = tid; i < DIMD; i += 256) xs[i] = xr[i] - bdec[i];
  int c = min(cnt[row], CAP);
  float mya = -3.0e38f; int mylat = 0x7fffffff;
  if (tid < c) { mya = candv[row * CAP + tid]; mylat = cand[row * CAP + tid]; }
  sv[tid] = mya;
  if (tid == 0) a32s = -3.0e38f;
  __syncthreads();
  // approx rank -> a32 (32nd-largest approx; ties by slot idx, margin covers)
  if (tid < c) {
    int r = 0;
    for (int j = 0; j < c; j++) {
      float vj = sv[j];
      r += (vj > mya) || (vj == mya && j < tid);
    }
    if (r == KTOP - 1) a32s = mya;
  }
  __syncthreads();
  float cutoff = a32s - 0.008f * thr[row];    // a32s=-3e38 (c<32) -> all survive
  // exact BLIS KC=512 chain only for survivors (~34 threads)
  float myv = -3.0e38f;
  if (tid < c && mya >= cutoff) {
    const float* wr = w + (size_t)mylat * DIMD;
    const int pb[5] = {0, 512, 1024, 1536, 2048};
    float accv = 0.f;
#pragma unroll
    for (int p = 0; p < 4; p++) {
      float s = 0.f;
      for (int k = pb[p]; k < pb[p + 1]; k += 4) {
        float4 wv = *(const float4*)(wr + k);
        s = fmaf(xs[k],     wv.x, s);
        s = fmaf(xs[k + 1], wv.y, s);
        s = fmaf(xs[k + 2], wv.z, s);
        s = fmaf(xs[k + 3], wv.w, s);
      }
      accv += s;
    }
    myv = accv + benc[mylat];
  }
  sv[tid] = myv; sl[tid] = (myv > -2.9e38f) ? mylat : 0x7fffffff;
  if (tid < KTOP) { sa[tid] = 0.f; si[tid] = 0; }   // defaults for <32 survivors
  __syncthreads();
  // exact rank (ties: latent asc = stable top_k); ranks unique
  if (myv > -2.9e38f) {
    int rk = 0;
    for (int j = 0; j < c; j++) {
      float vj = sv[j]; int lj = sl[j];
      rk += (vj > myv) || (vj == myv && lj < mylat);
    }
    if (rk < KTOP) { sa[rk] = myv; si[rk] = mylat; }
  }
  __syncthreads();
  if (tid < KTOP) {
    out[(size_t)NR * DIMD + row * KTOP + tid] = sa[tid];
    out[(size_t)NR * DIMD + (size_t)NR * KTOP + row * KTOP + tid] = (float)si[tid];
  }
  // ---- fused sparse decode + e^2 ----
  int c0 = tid * 4, c1 = 1024 + tid * 4;
  float a00 = 0, a01 = 0, a02 = 0, a03 = 0, a10 = 0, a11 = 0, a12 = 0, a13 = 0;
  for (int k = 0; k < KTOP; k++) {
    const float* wr = wdec + (size_t)si[k] * DIMD;
    float av = sa[k];
    float4 w0 = *(const float4*)(wr + c0);
    float4 w1 = *(const float4*)(wr + c1);
    a00 += av * w0.x; a01 += av * w0.y; a02 += av * w0.z; a03 += av * w0.w;
    a10 += av * w1.x; a11 += av * w1.y; a12 += av * w1.z; a13 += av * w1.w;
  }
  float4 b0 = *(const float4*)(bdec + c0), b1 = *(const float4*)(bdec + c1);
  a00 += b0.x; a01 += b0.y; a02 += b0.z; a03 += b0.w;
  a10 += b1.x; a11 += b1.y; a12 += b1.z; a13 += b1.w;
  float4 x0 = *(const float4*)(xr + c0), x1 = *(const float4*)(xr + c1);
  float4 o0, o1;
  o0.x = a00; o0.y = a01; o0.z = a02; o0.w = a03;
  o1.x = a10; o1.y = a11; o1.z = a12; o1.w = a13;
  *(float4*)(out + (size_t)row * DIMD + c0) = o0;
  *(float4*)(out + (size_t)row * DIMD + c1) = o1;
  double es = 0.0; float e;
  e = x0.x - a00; es += (double)e * e; e = x0.y - a01; es += (double)e * e;
  e = x0.z - a02; es += (double)e * e; e = x0.w - a03; es += (double)e * e;
  e = x1.x - a10; es += (double)e * e; e = x1.y - a11; es += (double)e * e;
  e = x1.z - a12; es += (double)e * e; e = x1.w - a13; es += (double)e * e;
  red[tid] = es; __syncthreads();
  for (int o = 128; o > 0; o >>= 1) { if (tid < o) red[tid] += red[tid + o]; __syncthreads(); }
  if (tid == 0) atomicAdd(sume2, red[0]);
}

__global__ __launch_bounds__(256) void k_final(const double* __restrict__ colsum,
    const double* __restrict__ sumx2, const double* __restrict__ sume2,
    float* __restrict__ out) {
  int tid = threadIdx.x;
  double s = 0.0;
  for (int i = tid; i < DIMD; i += 256) { double v = colsum[i]; s += v * v; }
  __shared__ double red[256];
  red[tid] = s; __syncthreads();
  for (int o = 128; o > 0; o >>= 1) { if (tid < o) red[tid] += red[tid + o]; __syncthreads(); }
  if (tid == 0) {
    double tv = *sumx2 - red[0] / (double)NR;
    double fvu = *sume2 / tv;
    size_t base = (size_t)NR * DIMD + 2 * (size_t)NR * KTOP;
    out[base] = (float)fvu;
    out[base + 1] = 0.f;
    out[base + 2] = 0.f;
  }
}

extern "C" void kernel_launch(void* const* d_in, const int* in_sizes, int n_in,
                              void* d_out, int out_size, void* d_ws, size_t ws_size,
                              hipStream_t stream) {
  const float* x    = (const float*)d_in[0];
  const float* wenc = (const float*)d_in[1];
  const float* benc = (const float*)d_in[2];
  const float* wdec = (const float*)d_in[3];
  const float* bdec = (const float*)d_in[4];
  float* out = (float*)d_out;
  char* ws = (char*)d_ws;

  unsigned short* xb  = (unsigned short*)(ws + 0);              // 16,777,216
  float* thr          = (float*)(ws + 16777216);                // 16,384
  int* cnt            = (int*)(ws + 16793600);                  // 16,384
  int* cand           = (int*)(ws + 16809984);                  // 3,670,016
  double* colsum      = (double*)(ws + 21528576);               // 16,384
  double* sumx2       = (double*)(ws + 21544960);               // 8
  double* sume2       = sumx2 + 1;                              // 8
  unsigned short* wb  = (unsigned short*)(ws + 22020096);       // 134,217,728
  float* candv        = (float*)(ws + 156237824);               // 3,670,016

  hipMemsetAsync(cnt, 0, 4096 * 4, stream);
  hipMemsetAsync(colsum, 0, 2048 * 8 + 16, stream);

  k_rowstats<<<NR, 256, 0, stream>>>(x, bdec, xb, thr, sumx2);
  k_colsum<<<dim3(8, 64), 256, 0, stream>>>(x, colsum);
  k_convw<<<2048, 256, 0, stream>>>(wenc, wb);
  k_gemm3<<<2048, 512, 0, stream>>>(xb, wb, benc, thr, cnt, cand, candv);
  k_refine_saeout<<<NR, 256, 0, stream>>>(x, bdec, wenc, benc, cnt, cand, candv, thr, wdec, out, sume2);
  k_final<<<1, 256, 0, stream>>>(colsum, sumx2, sume2, out);
}